// Round 4
// baseline (42.955 us; speedup 1.0000x reference)
//
#include <hip/hip_runtime.h>

// DCN cross stack collapsed (validated rounds 1-3):
//   u_k = x0.w_k, e_k = d_k.w_k (d_k = sum_{j<k} b_j), c_{k+1} = c_k(1+u_k)+e_k
//   out[t] = c_4 * (x0 . Wout[:,t]) + d_4.Wout[:,t] + bo[t]
//
// Round-4 structure: LANE-PER-ROW, 4-way F-split across the block's waves.
// Block(256thr) = 64 rows; wave w handles f in [128w,128w+128). All 12 dots
// lane-local (no cross-lane reduce in main loop). Weight addresses are
// wave-uniform (readfirstlane) -> SGPR s_load stream, zero weight VGPRs.
// Per lane x-loads: 16 consecutive floats per iter = one 64B line, 4 dwordx4.
// Combine 4 wave-partials (12/row) through 12.5 KB LDS; wave 0 does epilogue.

typedef float v4f __attribute__((ext_vector_type(4)));

template<int CTRL>
__device__ __forceinline__ float dpp_add(float v) {
  int t = __builtin_amdgcn_update_dpp(0, __float_as_int(v), CTRL, 0xF, 0xF, true);
  return v + __int_as_float(t);
}
// Full 64-lane sum, result valid in lane 63 (VALU-only).
__device__ __forceinline__ float wave_reduce(float v) {
  v = dpp_add<0x111>(v); v = dpp_add<0x112>(v); v = dpp_add<0x114>(v);
  v = dpp_add<0x118>(v); v = dpp_add<0x142>(v); v = dpp_add<0x143>(v);
  return v;
}

__global__ __launch_bounds__(256, 4) void cross_split(
    const float* __restrict__ x, const float* __restrict__ cw,
    const float* __restrict__ cb, const float* __restrict__ Wo,
    const float* __restrict__ bo, float* __restrict__ out)
{
  __shared__ float part[4][64][12];  // per-wave 12 dot partials per row
  __shared__ float egs[4][12];       // per-wave e1,e2,e3,g[0..7] partials

  const int tid  = threadIdx.x;
  const int lane = tid & 63;
  const int wv   = tid >> 6;
  const int fb   = __builtin_amdgcn_readfirstlane(wv << 7);  // wave's f base
  const int row  = (blockIdx.x << 6) + lane;

  // ---- Phase A: e/g partials over this wave's f-slice (2 f per lane) ----
  {
    float e1p = 0.f, e2p = 0.f, e3p = 0.f;
    float gp[8] = {0.f,0.f,0.f,0.f,0.f,0.f,0.f,0.f};
    const int f = fb + (lane << 1);
    #pragma unroll
    for (int j = 0; j < 2; ++j) {
      const int fj = f + j;
      const float b0 = cb[fj], b1 = cb[512 + fj], b2 = cb[1024 + fj], b3 = cb[1536 + fj];
      const float d1 = b0, d2 = d1 + b1, d3 = d2 + b2, d4 = d3 + b3;
      e1p = fmaf(d1, cw[512 + fj], e1p);
      e2p = fmaf(d2, cw[1024 + fj], e2p);
      e3p = fmaf(d3, cw[1536 + fj], e3p);
      const float* wr = Wo + (fj << 3);
      #pragma unroll
      for (int t = 0; t < 8; ++t) gp[t] = fmaf(d4, wr[t], gp[t]);
    }
    e1p = wave_reduce(e1p); e2p = wave_reduce(e2p); e3p = wave_reduce(e3p);
    #pragma unroll
    for (int t = 0; t < 8; ++t) gp[t] = wave_reduce(gp[t]);
    if (lane == 63) {
      egs[wv][0] = e1p; egs[wv][1] = e2p; egs[wv][2] = e3p;
      #pragma unroll
      for (int t = 0; t < 8; ++t) egs[wv][3 + t] = gp[t];
    }
  }

  // ---- Phase B: 12 lane-local dots over 128 f, scalar weights ----
  float u0 = 0.f, u1 = 0.f, u2 = 0.f, u3 = 0.f;
  float q[8] = {0.f,0.f,0.f,0.f,0.f,0.f,0.f,0.f};
  const float* xr  = x + (size_t)row * 512 + fb;
  const float* cw0 = cw + fb;          // SGPR base
  const float* Wo0 = Wo + (fb << 3);   // SGPR base

#define LOADX(R0,R1,R2,R3,i) do {                 \
    R0 = *(const v4f*)(xr + (i) * 16 + 0);        \
    R1 = *(const v4f*)(xr + (i) * 16 + 4);        \
    R2 = *(const v4f*)(xr + (i) * 16 + 8);        \
    R3 = *(const v4f*)(xr + (i) * 16 + 12);       \
  } while (0)

#define COMP1(V, i, qd) do {                                         \
    _Pragma("unroll")                                                \
    for (int e = 0; e < 4; ++e) {                                    \
      const int fl = (i) * 16 + (qd) * 4 + e;                        \
      const float xe = V[e];                                         \
      u0 = fmaf(xe, cw0[fl], u0);                                    \
      u1 = fmaf(xe, cw0[512 + fl], u1);                              \
      u2 = fmaf(xe, cw0[1024 + fl], u2);                             \
      u3 = fmaf(xe, cw0[1536 + fl], u3);                             \
      _Pragma("unroll")                                              \
      for (int t = 0; t < 8; ++t)                                    \
        q[t] = fmaf(xe, Wo0[(fl << 3) + t], q[t]);                   \
    }                                                                \
  } while (0)

#define COMP(A0,A1,A2,A3,i) do { COMP1(A0,i,0); COMP1(A1,i,1);       \
                                 COMP1(A2,i,2); COMP1(A3,i,3); } while (0)

  v4f a0, a1, a2, a3, b0, b1, b2, b3;
  LOADX(a0, a1, a2, a3, 0);
  #pragma unroll
  for (int ii = 0; ii < 4; ++ii) {
    LOADX(b0, b1, b2, b3, 2 * ii + 1);
    COMP(a0, a1, a2, a3, 2 * ii);
    if (ii < 3) {
      LOADX(a0, a1, a2, a3, 2 * ii + 2);
      COMP(b0, b1, b2, b3, 2 * ii + 1);
    }
  }
  COMP(b0, b1, b2, b3, 7);
#undef LOADX
#undef COMP1
#undef COMP

  // ---- publish partials ----
  {
    v4f p0, p1, p2;
    p0[0] = u0; p0[1] = u1; p0[2] = u2; p0[3] = u3;
    #pragma unroll
    for (int t = 0; t < 4; ++t) { p1[t] = q[t]; p2[t] = q[4 + t]; }
    float* dst = &part[wv][lane][0];
    *(v4f*)(dst + 0) = p0;
    *(v4f*)(dst + 4) = p1;
    *(v4f*)(dst + 8) = p2;
  }
  __syncthreads();

  // ---- Phase C: wave 0 combines + epilogue + store ----
  if (wv == 0) {
    const int r = lane;
    float s[12];
    #pragma unroll
    for (int j = 0; j < 12; ++j)
      s[j] = part[0][r][j] + part[1][r][j] + part[2][r][j] + part[3][r][j];
    const float e1 = egs[0][0] + egs[1][0] + egs[2][0] + egs[3][0];
    const float e2 = egs[0][1] + egs[1][1] + egs[2][1] + egs[3][1];
    const float e3 = egs[0][2] + egs[1][2] + egs[2][2] + egs[3][2];
    const float c1 = 1.f + s[0];
    const float c2 = fmaf(c1, s[1], c1) + e1;
    const float c3 = fmaf(c2, s[2], c2) + e2;
    const float c4 = fmaf(c3, s[3], c3) + e3;
    v4f o0, o1;
    #pragma unroll
    for (int t = 0; t < 4; ++t) {
      const float g0 = egs[0][3 + t] + egs[1][3 + t] + egs[2][3 + t] + egs[3][3 + t] + bo[t];
      const float g1 = egs[0][7 + t] + egs[1][7 + t] + egs[2][7 + t] + egs[3][7 + t] + bo[4 + t];
      o0[t] = fmaf(c4, s[4 + t], g0);
      o1[t] = fmaf(c4, s[8 + t], g1);
    }
    float* op = out + ((size_t)((blockIdx.x << 6) + r) << 3);
    *(v4f*)(op)     = o0;
    *(v4f*)(op + 4) = o1;
  }
}

extern "C" void kernel_launch(void* const* d_in, const int* in_sizes, int n_in,
                              void* d_out, int out_size, void* d_ws, size_t ws_size,
                              hipStream_t stream) {
  const float* x  = (const float*)d_in[0];
  const float* cw = (const float*)d_in[1];
  const float* cb = (const float*)d_in[2];
  const float* Wo = (const float*)d_in[3];
  const float* bo = (const float*)d_in[4];
  float* out = (float*)d_out;
  const int B = in_sizes[0] / 512;          // 65536
  hipLaunchKernelGGL(cross_split, dim3(B >> 6), dim3(256), 0, stream,
                     x, cw, cb, Wo, bo, out);
}

// Round 5
// 30.630 us; speedup vs baseline: 1.4024x; 1.4024x over previous
//
#include <hip/hip_runtime.h>
#include <hip/hip_bf16.h>

// DCN cross stack collapsed (validated rounds 1-4):
//   u_k = x0.w_k, e_k = d_k.w_k (d_k = sum_{j<k} b_j), c_{k+1} = c_k(1+u_k)+e_k
//   out[t] = c_4 * (x0 . Wout[:,t]) + d_4.Wout[:,t] + bo[t]
//
// Round-5: the 12 dots/row = tall-skinny GEMM X[65536x512] @ Wcat[512x12pad16]
// done with mfma_f32_16x16x32_bf16, split-bf16 3-term product for fp32-level
// accuracy (AhBh + AlBh + AhBl). B-fragments (hi/lo) built once per block in
// LDS; per K-step a wave does 2 coalesced dwordx4 x-loads, converts, 2
// ds_read_b128, 3 MFMA. VALU carries only loads+converts; reduction tax gone.
// Block = 256 thr = 4 waves = 4 row-tiles of 16; grid 1024 blocks.

typedef float v4f __attribute__((ext_vector_type(4)));
typedef float f32x4 __attribute__((ext_vector_type(4)));
typedef short s16x8 __attribute__((ext_vector_type(8)));

__device__ __forceinline__ short f2bf(float v) {          // RTNE fp32->bf16
  return __builtin_bit_cast(short, __float2bfloat16(v));
}
__device__ __forceinline__ float bf2f(short s) {
  return __uint_as_float(((unsigned)(unsigned short)s) << 16);
}

template<int CTRL>
__device__ __forceinline__ float dpp_add(float v) {
  int t = __builtin_amdgcn_update_dpp(0, __float_as_int(v), CTRL, 0xF, 0xF, true);
  return v + __int_as_float(t);
}
__device__ __forceinline__ float wave_reduce(float v) {   // total in lane 63
  v = dpp_add<0x111>(v); v = dpp_add<0x112>(v); v = dpp_add<0x114>(v);
  v = dpp_add<0x118>(v); v = dpp_add<0x142>(v); v = dpp_add<0x143>(v);
  return v;
}

__global__ __launch_bounds__(256, 4) void cross_mfma(
    const float* __restrict__ x, const float* __restrict__ cw,
    const float* __restrict__ cb, const float* __restrict__ Wo,
    const float* __restrict__ bo, float* __restrict__ out)
{
  __shared__ s16x8 Bh[16][64];     // 16 KB  B-frag hi per K-step per lane
  __shared__ s16x8 Bl[16][64];     // 16 KB  B-frag lo
  __shared__ float ct[4][16][17];  // 4.25 KB C transpose scratch per wave
  __shared__ float egs[12];        // e1,e2,e3, g[0..7]

  const int tid = threadIdx.x, lane = tid & 63, wv = tid >> 6;

  // ---- build B fragments: Wcat[k][c] (c:0-3 cross_w rows, 4-11 Wout cols) --
  for (int slot = tid; slot < 1024; slot += 256) {
    const int s = slot >> 6, l = slot & 63;
    const int c = l & 15, k0 = s * 32 + ((l >> 4) << 3);
    float f[8];
    if (c < 4) {
      v4f a = *(const v4f*)(cw + c * 512 + k0);
      v4f b = *(const v4f*)(cw + c * 512 + k0 + 4);
      #pragma unroll
      for (int j = 0; j < 4; ++j) { f[j] = a[j]; f[4 + j] = b[j]; }
    } else if (c < 12) {
      #pragma unroll
      for (int j = 0; j < 8; ++j) f[j] = Wo[(k0 + j) * 8 + (c - 4)];
    } else {
      #pragma unroll
      for (int j = 0; j < 8; ++j) f[j] = 0.f;
    }
    s16x8 h, lo;
    #pragma unroll
    for (int j = 0; j < 8; ++j) {
      h[j]  = f2bf(f[j]);
      lo[j] = f2bf(f[j] - bf2f(h[j]));
    }
    Bh[s][l] = h;
    Bl[s][l] = lo;
  }

  // ---- wave 0: fp32 constants e1,e2,e3, g[0..7] ---------------------------
  if (wv == 0) {
    const int f0 = lane << 3;
    v4f d0a = *(const v4f*)(cb + f0),        d0b = *(const v4f*)(cb + f0 + 4);
    v4f c1a = *(const v4f*)(cb + 512 + f0),  c1b = *(const v4f*)(cb + 512 + f0 + 4);
    v4f c2a = *(const v4f*)(cb + 1024 + f0), c2b = *(const v4f*)(cb + 1024 + f0 + 4);
    v4f c3a = *(const v4f*)(cb + 1536 + f0), c3b = *(const v4f*)(cb + 1536 + f0 + 4);
    v4f w1a = *(const v4f*)(cw + 512 + f0),  w1b = *(const v4f*)(cw + 512 + f0 + 4);
    v4f w2a = *(const v4f*)(cw + 1024 + f0), w2b = *(const v4f*)(cw + 1024 + f0 + 4);
    v4f w3a = *(const v4f*)(cw + 1536 + f0), w3b = *(const v4f*)(cw + 1536 + f0 + 4);
    float e1p = 0.f, e2p = 0.f, e3p = 0.f;
    v4f dA = d0a, dB = d0b;
    #pragma unroll
    for (int e = 0; e < 4; ++e) e1p += dA[e] * w1a[e] + dB[e] * w1b[e];
    dA += c1a; dB += c1b;
    #pragma unroll
    for (int e = 0; e < 4; ++e) e2p += dA[e] * w2a[e] + dB[e] * w2b[e];
    dA += c2a; dB += c2b;
    #pragma unroll
    for (int e = 0; e < 4; ++e) e3p += dA[e] * w3a[e] + dB[e] * w3b[e];
    dA += c3a; dB += c3b;
    float gp[8] = {0.f,0.f,0.f,0.f,0.f,0.f,0.f,0.f};
    #pragma unroll
    for (int e = 0; e < 4; ++e) {
      const float* wra = Wo + (f0 + e) * 8;
      const float* wrb = Wo + (f0 + 4 + e) * 8;
      #pragma unroll
      for (int t = 0; t < 8; ++t) gp[t] += dA[e] * wra[t] + dB[e] * wrb[t];
    }
    e1p = wave_reduce(e1p); e2p = wave_reduce(e2p); e3p = wave_reduce(e3p);
    #pragma unroll
    for (int t = 0; t < 8; ++t) gp[t] = wave_reduce(gp[t]);
    if (lane == 63) {
      egs[0] = e1p; egs[1] = e2p; egs[2] = e3p;
      #pragma unroll
      for (int t = 0; t < 8; ++t) egs[3 + t] = gp[t] + bo[t];
    }
  }
  __syncthreads();

  // ---- main: per wave one 16-row tile, 16 K-steps of 32 -------------------
  const int row0 = (blockIdx.x << 6) + (wv << 4);
  const float* xr = x + (size_t)(row0 + (lane & 15)) * 512 + ((lane >> 4) << 3);
  const float e1 = egs[0], e2 = egs[1], e3 = egs[2];
  float gg[8];
  #pragma unroll
  for (int t = 0; t < 8; ++t) gg[t] = egs[3 + t];

  f32x4 acc = {0.f, 0.f, 0.f, 0.f};
  v4f pa = *(const v4f*)(xr), pb = *(const v4f*)(xr + 4);
  #pragma unroll
  for (int s = 0; s < 16; ++s) {
    v4f na = pa, nb = pb;
    if (s < 15) {
      na = *(const v4f*)(xr + (s + 1) * 32);
      nb = *(const v4f*)(xr + (s + 1) * 32 + 4);
    }
    const s16x8 bh = Bh[s][lane];
    const s16x8 bl = Bl[s][lane];
    s16x8 ah, al;
    #pragma unroll
    for (int j = 0; j < 4; ++j) {
      ah[j]     = f2bf(pa[j]); al[j]     = f2bf(pa[j] - bf2f(ah[j]));
      ah[4 + j] = f2bf(pb[j]); al[4 + j] = f2bf(pb[j] - bf2f(ah[4 + j]));
    }
    acc = __builtin_amdgcn_mfma_f32_16x16x32_bf16(ah, bh, acc, 0, 0, 0);
    acc = __builtin_amdgcn_mfma_f32_16x16x32_bf16(al, bh, acc, 0, 0, 0);
    acc = __builtin_amdgcn_mfma_f32_16x16x32_bf16(ah, bl, acc, 0, 0, 0);
    pa = na; pb = nb;
  }

  // ---- epilogue: transpose C via wave-private LDS, recurrence, store ------
  #pragma unroll
  for (int j = 0; j < 4; ++j)
    ct[wv][((lane >> 4) << 2) + j][lane & 15] = acc[j];
  if (lane < 16) {
    const float u0 = ct[wv][lane][0], u1 = ct[wv][lane][1];
    const float u2 = ct[wv][lane][2], u3 = ct[wv][lane][3];
    const float cc1 = 1.f + u0;
    const float cc2 = fmaf(cc1, u1, cc1) + e1;
    const float cc3 = fmaf(cc2, u2, cc2) + e2;
    const float cc4 = fmaf(cc3, u3, cc3) + e3;
    v4f o0, o1;
    #pragma unroll
    for (int t = 0; t < 4; ++t) {
      o0[t] = fmaf(cc4, ct[wv][lane][4 + t], gg[t]);
      o1[t] = fmaf(cc4, ct[wv][lane][8 + t], gg[4 + t]);
    }
    float* op = out + (size_t)(row0 + lane) * 8;
    *(v4f*)(op)     = o0;
    *(v4f*)(op + 4) = o1;
  }
}

extern "C" void kernel_launch(void* const* d_in, const int* in_sizes, int n_in,
                              void* d_out, int out_size, void* d_ws, size_t ws_size,
                              hipStream_t stream) {
  const float* x  = (const float*)d_in[0];
  const float* cw = (const float*)d_in[1];
  const float* cb = (const float*)d_in[2];
  const float* Wo = (const float*)d_in[3];
  const float* bo = (const float*)d_in[4];
  float* out = (float*)d_out;
  const int B = in_sizes[0] / 512;          // 65536
  hipLaunchKernelGGL(cross_mfma, dim3(B >> 6), dim3(256), 0, stream,
                     x, cw, cb, Wo, bo, out);
}